// Round 8
// baseline (329.824 us; speedup 1.0000x reference)
//
#include <hip/hip_runtime.h>
#include <stdint.h>

#define MDIM 8192
#define NDIM 4096
#define KDIM 4096
#define QBLK 128
#define KB 32   // KDIM / QBLK
#define NB 32   // NDIM / QBLK

// ---- 256x256 gemm geometry ----
#define BM 256
#define BN 256
#define BK 64
#define NT (KDIM / BK)          // 64 K-tiles
#define TILESZ (BM * BK)        // 16384 B per operand tile buffer

typedef __attribute__((ext_vector_type(4))) int int32x4;
typedef __attribute__((ext_vector_type(4))) float f32x4;

#define GPTR(p) ((const __attribute__((address_space(1))) void*)(p))
#define LPTR(p) ((__attribute__((address_space(3))) void*)(p))

__device__ __forceinline__ int quant1(float v, float s) {
  float q = rintf(v / s);
  q = fminf(fmaxf(q, -127.f), 127.f);
  return (int)q;
}

// ---------------- activation quant: one wave per (row m, k-block kb) ----------
__global__ __launch_bounds__(256) void quant_x_kernel(
    const float* __restrict__ x, int8_t* __restrict__ xq, float* __restrict__ xsT) {
  const int lane = threadIdx.x & 63;
  const int wid = blockIdx.x * 4 + (threadIdx.x >> 6);
  const int m = wid >> 5;    // / KB
  const int kb = wid & 31;   // % KB
  const size_t base = (size_t)m * KDIM + (size_t)kb * QBLK;
  const float2 v = *reinterpret_cast<const float2*>(x + base + lane * 2);
  float amax = fmaxf(fabsf(v.x), fabsf(v.y));
#pragma unroll
  for (int off = 32; off; off >>= 1)
    amax = fmaxf(amax, __shfl_xor(amax, off));
  const float scale = fmaxf(amax / 127.0f, 1e-12f);
  const int ia = quant1(v.x, scale);
  const int ib = quant1(v.y, scale);
  const uint16_t packed = (uint16_t)((ia & 0xff) | ((ib & 0xff) << 8));
  *reinterpret_cast<uint16_t*>(xq + base + lane * 2) = packed;
  if (lane == 0) xsT[(size_t)kb * MDIM + m] = scale;
}

// ---------------- weight quant: one 256-thread block per 128x128 block --------
__global__ __launch_bounds__(256) void quant_w_kernel(
    const float* __restrict__ w, int8_t* __restrict__ wq, float* __restrict__ ws) {
  const int nb = blockIdx.x >> 5;   // / KB
  const int kb = blockIdx.x & 31;   // % KB
  const int tid = threadIdx.x;
  const int lane = tid & 63;
  const int wv = tid >> 6;
  __shared__ float red[4];

  float amax = 0.f;
  float4 vals[16];
#pragma unroll
  for (int i = 0; i < 16; ++i) {
    const int idx4 = tid + i * 256;         // 4096 float4 per block
    const int row = idx4 >> 5;
    const int c4 = idx4 & 31;
    const float4 v = *reinterpret_cast<const float4*>(
        w + (size_t)(nb * QBLK + row) * KDIM + (size_t)kb * QBLK + c4 * 4);
    vals[i] = v;
    amax = fmaxf(amax, fmaxf(fmaxf(fabsf(v.x), fabsf(v.y)),
                             fmaxf(fabsf(v.z), fabsf(v.w))));
  }
#pragma unroll
  for (int off = 32; off; off >>= 1)
    amax = fmaxf(amax, __shfl_xor(amax, off));
  if (lane == 0) red[wv] = amax;
  __syncthreads();
  amax = fmaxf(fmaxf(red[0], red[1]), fmaxf(red[2], red[3]));
  const float scale = fmaxf(amax / 127.0f, 1e-12f);

#pragma unroll
  for (int i = 0; i < 16; ++i) {
    const int idx4 = tid + i * 256;
    const int row = idx4 >> 5;
    const int c4 = idx4 & 31;
    const float4 v = vals[i];
    const int qa = quant1(v.x, scale);
    const int qb = quant1(v.y, scale);
    const int qc = quant1(v.z, scale);
    const int qd = quant1(v.w, scale);
    const uint32_t packed = (uint32_t)(qa & 0xff) | ((uint32_t)(qb & 0xff) << 8) |
                            ((uint32_t)(qc & 0xff) << 16) | ((uint32_t)(qd & 0xff) << 24);
    *reinterpret_cast<uint32_t*>(
        wq + (size_t)(nb * QBLK + row) * KDIM + (size_t)kb * QBLK + c4 * 4) = packed;
  }
  if (tid == 0) ws[nb * KB + kb] = scale;
}

// ---------------- int8 blockwise GEMM: 256x256, 8 waves, triple-buffered -----
// - K-tile = 64: one mfma_i32_16x16x64_i8 per fragment, zeroc C-in (no init,
//   no chaining). Fixup per K-tile (scale applied to each 64-half of the
//   quant block; f32-rounding-equivalent to per-128 fixup).
// - LDS tiles [256 rows][64 cols] i8, 16B-chunk swizzle: phys_chunk =
//   log_chunk ^ (row&3) ^ ((row>>2)&3)  -> 2-way bank aliasing (free).
//   Linear LDS dest + inverse-swizzled global source (global_load_lds).
// - Triple buffer: stage tile t+2 during tile t; ONE s_waitcnt vmcnt(4) +
//   ONE s_barrier per tile (certifies t+1's loads, issued a full tile ago;
//   never drains the fresh loads).
__global__ __launch_bounds__(512, 2) void gemm_i8_kernel(
    const int8_t* __restrict__ Aq, const int8_t* __restrict__ Bq,
    const float* __restrict__ xsT, const float* __restrict__ wsp,
    const float* __restrict__ bias, float* __restrict__ C) {
  __shared__ int8_t As[3 * TILESZ];   // 48 KB
  __shared__ int8_t Bs[3 * TILESZ];   // 48 KB
  __shared__ float xsl[KB * BM];      // 32 KB: xs[kb][row]

  const int tid = threadIdx.x;
  const int lane = tid & 63;
  const int wid = tid >> 6;        // 0..7
  const int wm = wid >> 2;         // wave M 0..1  (128 rows each)
  const int wn = wid & 3;          // wave N 0..3  (64 cols each)
  const int l15 = lane & 15;
  const int lhi = lane >> 4;       // 0..3

  // XCD-chunked block swizzle (512 blocks, 8 XCDs, 64 each)
  const int id = blockIdx.x;
  const int swz = (id & 7) * 64 + (id >> 3);
  const int bm = swz >> 4;               // 0..31
  const int bn = swz & 15;               // 0..15
  const int brow = bm * BM;
  const int bcol = bn * BN;
  const int nb2 = bn * 2 + (wn >> 1);    // quant N-block of this wave

  f32x4 accf[8][4];
#pragma unroll
  for (int m = 0; m < 8; ++m)
#pragma unroll
    for (int n = 0; n < 4; ++n) accf[m][n] = (f32x4){0.f, 0.f, 0.f, 0.f};

  const int32x4 zeroc = {0, 0, 0, 0};

  // ---- staging thread constants (2 issue-groups per operand tile) ----
  int asrc_off[2], ldst_off[2];
#pragma unroll
  for (int g = 0; g < 2; ++g) {
    const int idx = g * 512 + tid;        // 0..1023 16B chunks
    const int row = idx >> 2;             // 0..255
    const int c = idx & 3;
    const int csrc = c ^ (row & 3) ^ ((row >> 2) & 3);
    asrc_off[g] = row * KDIM + csrc * 16;
    ldst_off[g] = idx * 16;
  }
  const int8_t* abase = Aq + (size_t)brow * KDIM;
  const int8_t* bbase = Bq + (size_t)bcol * KDIM;

  // ---- fragment read bases (swizzle is lane-only: rows step by 16) ----
  const int s_lane = (l15 & 3) ^ ((l15 >> 2) & 3);
  const int a_rd = (wm * 128 + l15) * 64 + ((lhi ^ s_lane) * 16);
  const int b_rd = (wn * 64 + l15) * 64 + ((lhi ^ s_lane) * 16);
  const int xrow = wm * 128 + lhi * 4;   // + mi*16

#define STAGE_A(wb_, k2_)                                                       \
  _Pragma("unroll") for (int g = 0; g < 2; ++g)                                 \
      __builtin_amdgcn_global_load_lds(GPTR(abase + (size_t)(k2_) + asrc_off[g]),\
                                       LPTR(As + (wb_) * TILESZ + ldst_off[g]), \
                                       16, 0, 0);
#define STAGE_B(wb_, k2_)                                                       \
  _Pragma("unroll") for (int g = 0; g < 2; ++g)                                 \
      __builtin_amdgcn_global_load_lds(GPTR(bbase + (size_t)(k2_) + asrc_off[g]),\
                                       LPTR(Bs + (wb_) * TILESZ + ldst_off[g]), \
                                       16, 0, 0);

  // ---- prologue: stage tiles 0,1; fill xsl; full sync ----
  STAGE_A(0, 0); STAGE_B(0, 0);
  STAGE_A(1, BK); STAGE_B(1, BK);
#pragma unroll
  for (int i = 0; i < 4; ++i) {
    const int idx = i * 512 + tid;        // 2048 f32x4 = 32 kb x 64 groups
    const int kb_ = idx >> 6;
    const int r4 = idx & 63;
    const f32x4 v = *reinterpret_cast<const f32x4*>(
        xsT + (size_t)kb_ * MDIM + brow + r4 * 4);
    *reinterpret_cast<f32x4*>(xsl + kb_ * BM + r4 * 4) = v;
  }
  __syncthreads();

  // ---- main loop ----
  int rb = 0;                 // read buffer  = t % 3
  int wb = 2;                 // write buffer = (t+2) % 3
  for (int t = 0; t < NT; ++t) {
    const int kb = t >> 1;
    const int k2 = (t + 2 < NT ? t + 2 : NT - 1) * BK;   // clamped (dummy at tail)
    const int8_t* asb = As + rb * TILESZ;
    const int8_t* bsb = Bs + rb * TILESZ;

    int32x4 bf[4];
#pragma unroll
    for (int n = 0; n < 4; ++n)
      bf[n] = *reinterpret_cast<const int32x4*>(bsb + b_rd + n * 1024);
    const float sw = wsp[nb2 * KB + kb];   // wave-uniform (s_load)

    STAGE_A(wb, k2);

#pragma unroll
    for (int mi = 0; mi < 8; ++mi) {
      const int32x4 af = *reinterpret_cast<const int32x4*>(asb + a_rd + mi * 1024);
      const f32x4 sx = *reinterpret_cast<const f32x4*>(xsl + kb * BM + xrow + mi * 16);
      const f32x4 sxw = sx * sw;
      int32x4 p0, p1, p2, p3;
      __builtin_amdgcn_s_setprio(1);
      p0 = __builtin_amdgcn_mfma_i32_16x16x64_i8(af, bf[0], zeroc, 0, 0, 0);
      p1 = __builtin_amdgcn_mfma_i32_16x16x64_i8(af, bf[1], zeroc, 0, 0, 0);
      p2 = __builtin_amdgcn_mfma_i32_16x16x64_i8(af, bf[2], zeroc, 0, 0, 0);
      p3 = __builtin_amdgcn_mfma_i32_16x16x64_i8(af, bf[3], zeroc, 0, 0, 0);
      __builtin_amdgcn_s_setprio(0);
      accf[mi][0] += __builtin_convertvector(p0, f32x4) * sxw;
      accf[mi][1] += __builtin_convertvector(p1, f32x4) * sxw;
      accf[mi][2] += __builtin_convertvector(p2, f32x4) * sxw;
      accf[mi][3] += __builtin_convertvector(p3, f32x4) * sxw;
      if (mi == 3) { STAGE_B(wb, k2); }
    }

    asm volatile("s_waitcnt vmcnt(4)" ::: "memory");
    __builtin_amdgcn_s_barrier();
    asm volatile("" ::: "memory");

    rb = (rb == 2) ? 0 : rb + 1;
    wb = (wb == 2) ? 0 : wb + 1;
  }

  // ---- epilogue: bias + store ----
  float bn_[4];
  int coln[4];
#pragma unroll
  for (int n = 0; n < 4; ++n) {
    coln[n] = bcol + wn * 64 + n * 16 + l15;
    bn_[n] = bias[coln[n]];
  }
#pragma unroll
  for (int mi = 0; mi < 8; ++mi) {
#pragma unroll
    for (int r = 0; r < 4; ++r) {
      const int row = brow + wm * 128 + mi * 16 + lhi * 4 + r;
#pragma unroll
      for (int n = 0; n < 4; ++n)
        C[(size_t)row * NDIM + coln[n]] = ((const float*)&accf[mi][n])[r] + bn_[n];
    }
  }
#undef STAGE_A
#undef STAGE_B
}

extern "C" void kernel_launch(void* const* d_in, const int* in_sizes, int n_in,
                              void* d_out, int out_size, void* d_ws, size_t ws_size,
                              hipStream_t stream) {
  const float* x = (const float*)d_in[0];
  const float* w = (const float*)d_in[1];
  const float* bias = (const float*)d_in[2];
  float* out = (float*)d_out;

  char* base = (char*)d_ws;
  size_t off = 0;
  int8_t* xq = (int8_t*)(base + off); off += (size_t)MDIM * KDIM;          // 32 MB
  int8_t* wq = (int8_t*)(base + off); off += (size_t)NDIM * KDIM;          // 16 MB
  float* xsT = (float*)(base + off); off += (size_t)KB * MDIM * 4;         // 1 MB
  float* wsc = (float*)(base + off);                                       // 4 KB

  quant_x_kernel<<<(MDIM * KB) / 4, 256, 0, stream>>>(x, xq, xsT);
  quant_w_kernel<<<NB * KB, 256, 0, stream>>>(w, wq, wsc);
  gemm_i8_kernel<<<(MDIM / BM) * (NDIM / BN), 512, 0, stream>>>(xq, wq, xsT, wsc, bias, out);
}